// Round 10
// baseline (68.702 us; speedup 1.0000x reference)
//
#include <hip/hip_runtime.h>
#include <hip/hip_bf16.h>

#define NB 256
#define NK 32
#define NL 4096
#define NW (NB * 16)    // 4096 waves; each owns 256 consecutive l of one b
#define EPSV 1e-5f
#define PEAK_LAMBDA 0.005f
#define ORTHO_LAMBDA 20000.0f
#define LN2F 0.6931471805599453f

typedef __attribute__((ext_vector_type(8))) short short8;
typedef __attribute__((ext_vector_type(4))) float f32x4;

// ---------------- Kernel 1: single-wave blocks, zero LDS, zero barriers ------
// grid = 4096 x 64 threads (1 wave). Wave w: b = w>>4, l-segment [seg*256,
// seg*256+256). Two unrolled half-segments of 4 MFMA k-steps each (the proven
// NC=8 live set: 16 float4 in flight). Lanes load MFMA fragments (rows
// lane&15 / 16+(lane&15), 8 consecutive floats at (lane>>4)*8) DIRECTLY from
// global; fp32->bf16 by truncation (one v_perm_b32 per pair); argmax +
// sum(log2(a+eps)) fused on the same registers. Gram symmetry: G10 == G01^T.
// Per-wave partials go straight to global: no __syncthreads anywhere.
// NOTE: no min-waves launch-bound (round-5 spill) and no per-block
// threadfence/atomic tail (round-8 XCD-fence serialization).
__global__ __launch_bounds__(64) void k_main(const float* __restrict__ a,
                                             float* __restrict__ gram,
                                             float* __restrict__ rmax,
                                             int* __restrict__ ridx,
                                             float* __restrict__ rlogp) {
    const int w = blockIdx.x;
    const int b = w >> 4, seg = w & 15;
    const int lane = threadIdx.x;
    const int r0 = lane & 15, hi = lane >> 4;

    const float* __restrict__ rowA =
        a + ((size_t)b * NK + r0) * NL + seg * 256 + hi * 8;
    const float* __restrict__ rowB = rowA + 16 * (size_t)NL;
    const int lbase = seg * 256 + hi * 8;

    float mvA = -1.0f, mvB = -1.0f;
    int miA = 0, miB = 0;
    float lpA0 = 0.0f, lpA1 = 0.0f, lpB0 = 0.0f, lpB1 = 0.0f;
    f32x4 acc00 = {0.f,0.f,0.f,0.f}, acc01 = {0.f,0.f,0.f,0.f},
          acc11 = {0.f,0.f,0.f,0.f};

#pragma unroll
    for (int it = 0; it < 2; ++it) {
#pragma unroll
        for (int s = 0; s < 4; ++s) {
            const int off = it * 128 + s * 32;
            float4 a0 = *reinterpret_cast<const float4*>(rowA + off);
            float4 a1 = *reinterpret_cast<const float4*>(rowA + off + 4);
            float4 b0 = *reinterpret_cast<const float4*>(rowB + off);
            float4 b1 = *reinterpret_cast<const float4*>(rowB + off + 4);
            float va[8] = {a0.x, a0.y, a0.z, a0.w, a1.x, a1.y, a1.z, a1.w};
            float vb[8] = {b0.x, b0.y, b0.z, b0.w, b1.x, b1.y, b1.z, b1.w};
            const int l0 = lbase + off;
            union { unsigned u[4]; short8 s8; } fa, fb;
#pragma unroll
            for (int c2 = 0; c2 < 4; ++c2) {
                float v0 = va[2*c2], v1 = va[2*c2 + 1];
                float w0 = vb[2*c2], w1 = vb[2*c2 + 1];
                float xa0 = v0 + EPSV, xa1 = v1 + EPSV;
                float xb0 = w0 + EPSV, xb1 = w1 + EPSV;
                if (v0 > mvA) { mvA = v0; miA = l0 + 2*c2; }
                if (v1 > mvA) { mvA = v1; miA = l0 + 2*c2 + 1; }
                if (w0 > mvB) { mvB = w0; miB = l0 + 2*c2; }
                if (w1 > mvB) { mvB = w1; miB = l0 + 2*c2 + 1; }
                lpA0 += __log2f(xa0); lpA1 += __log2f(xa1);
                lpB0 += __log2f(xb0); lpB1 += __log2f(xb1);
                // pack hi16(xa0) | hi16(xa1)<<16 : one v_perm_b32 per pair
                fa.u[c2] = __builtin_amdgcn_perm(__float_as_uint(xa1),
                                                 __float_as_uint(xa0),
                                                 0x07060302u);
                fb.u[c2] = __builtin_amdgcn_perm(__float_as_uint(xb1),
                                                 __float_as_uint(xb0),
                                                 0x07060302u);
            }
            acc00 = __builtin_amdgcn_mfma_f32_16x16x32_bf16(fa.s8, fa.s8, acc00, 0, 0, 0);
            acc01 = __builtin_amdgcn_mfma_f32_16x16x32_bf16(fa.s8, fb.s8, acc01, 0, 0, 0);
            acc11 = __builtin_amdgcn_mfma_f32_16x16x32_bf16(fb.s8, fb.s8, acc11, 0, 0, 0);
        }
    }
    float lpA = (lpA0 + lpA1) * LN2F;
    float lpB = (lpB0 + lpB1) * LN2F;

    // ---- cross-lane per-row reduce: row r0 lives in lanes {r0,+16,+32,+48}
#pragma unroll
    for (int off = 16; off <= 32; off <<= 1) {
        float ov = __shfl_xor(mvA, off); int oi = __shfl_xor(miA, off);
        if (ov > mvA || (ov == mvA && oi < miA)) { mvA = ov; miA = oi; }
        ov = __shfl_xor(mvB, off); oi = __shfl_xor(miB, off);
        if (ov > mvB || (ov == mvB && oi < miB)) { mvB = ov; miB = oi; }
        lpA += __shfl_xor(lpA, off);
        lpB += __shfl_xor(lpB, off);
    }

    if (hi == 0) {   // lanes 0..15 hold rows r0 and 16+r0
        rmax[w * 32 + r0] = mvA;  ridx[w * 32 + r0] = miA;
        rlogp[w * 32 + r0] = lpA;
        rmax[w * 32 + 16 + r0] = mvB;  ridx[w * 32 + 16 + r0] = miB;
        rlogp[w * 32 + 16 + r0] = lpB;
    }
    // per-wave Gram partial. C/D layout (m89): col=lane&15, row=(lane>>4)*4+reg
    {
        const int rb2 = hi * 4;
#pragma unroll
        for (int r = 0; r < 4; ++r) {
            int gr = rb2 + r;
            gram[(size_t)w * 768 + gr * 16 + r0]       = acc00[r];
            gram[(size_t)w * 768 + 256 + gr * 16 + r0] = acc01[r];
            gram[(size_t)w * 768 + 512 + gr * 16 + r0] = acc11[r];
        }
    }
}

// ---------------- Kernel 2: parallel finalize (8704 x 64) ----------------
// Blocks 0..8191: one wave per (b,k) row — lanes 0..15 combine the 16
// per-wave partials, then the 64-wide Gaussian window maps 1:1 onto lanes
// (coalesced 256B read). Butterfly reductions, no LDS.
// Blocks 8192..8703: gram finalize — sum 16 wave partials for 384 elements,
// apply off-diag/2x weights, square, butterfly-reduce.
__global__ __launch_bounds__(64) void k_fin2(const float* __restrict__ a,
                                             const float* __restrict__ gram,
                                             const float* __restrict__ rmax,
                                             const int* __restrict__ ridx,
                                             const float* __restrict__ rlogp,
                                             float* __restrict__ rowkl,
                                             float* __restrict__ ortho_parts) {
    const int bid = blockIdx.x;
    const int lane = threadIdx.x;

    if (bid < NB * NK) {
        const int b = bid >> 5, k = bid & 31;
        float bv = -1.0f, lp = 0.0f; int bi = 0;
        if (lane < 16) {
            bv = rmax[(b * 16 + lane) * 32 + k];
            bi = ridx[(b * 16 + lane) * 32 + k];
            lp = rlogp[(b * 16 + lane) * 32 + k];
        }
#pragma unroll
        for (int off = 1; off <= 8; off <<= 1) {
            float ov = __shfl_xor(bv, off); int oi = __shfl_xor(bi, off);
            float ol = __shfl_xor(lp, off);
            if (ov > bv || (ov == bv && oi < bi)) { bv = ov; bi = oi; }
            lp += ol;
        }
        const int idx = __shfl(bi, 0);
        const float lpr = __shfl(lp, 0);

        // window: l = idx-31+lane, one element per lane
        const int l = idx - 31 + lane;
        const float d = (float)(lane - 31);
        const bool valid = (l >= 0) && (l < NL);
        const float g = valid ? __expf(d * d * (-1.0f / 4.5f)) : 0.0f;
        const float pv = valid
            ? a[((size_t)b * NK + k) * (size_t)NL + l] : 1.0f;
        float zs = g;
#pragma unroll
        for (int off = 1; off < 64; off <<= 1) zs += __shfl_xor(zs, off);
        const float rz = 1.0f / zs;
        float term = 0.0f;
        int nv = valid ? 1 : 0;
        if (valid) {
            float gg = g * rz;
            float tf = gg + EPSV;
            term = tf * __logf(tf) - gg * __logf(pv + EPSV);
        }
#pragma unroll
        for (int off = 1; off < 64; off <<= 1) {
            term += __shfl_xor(term, off);
            nv += __shfl_xor(nv, off);
        }
        if (lane == 0)
            rowkl[bid] = term + (float)(NL - nv) * (EPSV * __logf(EPSV))
                       - EPSV * lpr;
    } else {
        const int gid = bid - NB * NK;   // 0..511; 384 elements each
        float local = 0.0f;
#pragma unroll
        for (int j = 0; j < 6; ++j) {
            int eg = gid * 384 + j * 64 + lane;     // 0..196607
            int b = eg / 768, e = eg - b * 768;
            float s = 0.0f;
#pragma unroll
            for (int ww = 0; ww < 16; ++ww)
                s += gram[(size_t)(b * 16 + ww) * 768 + e];
            int blk = e >> 8, idx2 = e & 255, kk = idx2 >> 4, mm = idx2 & 15;
            float wgt = (blk == 1) ? 2.0f : ((kk == mm) ? 0.0f : 1.0f);
            local += wgt * s * s;
        }
#pragma unroll
        for (int off = 1; off < 64; off <<= 1) local += __shfl_xor(local, off);
        if (lane == 0) ortho_parts[gid] = local;
    }
}

// ---------------- Kernel 3: final 8192+512 -> scalars ----------------
__global__ __launch_bounds__(256) void k_final(const float* __restrict__ rowkl,
                                               const float* __restrict__ ortho_parts,
                                               float* __restrict__ out) {
    const int tid = threadIdx.x;
    __shared__ float s1[256], s2[256];
    float pk = 0.0f, ot = 0.0f;
#pragma unroll
    for (int j = 0; j < 32; ++j) pk += rowkl[tid + 256 * j];
    ot = ortho_parts[tid] + ortho_parts[tid + 256];
    s1[tid] = pk;
    s2[tid] = ot;
    __syncthreads();
    for (int s = 128; s > 0; s >>= 1) {
        if (tid < s) { s1[tid] += s1[tid + s]; s2[tid] += s2[tid + s]; }
        __syncthreads();
    }
    if (tid == 0) {
        float peak = PEAK_LAMBDA * s1[0];
        float ortho = ORTHO_LAMBDA * (s2[0] / (float)(NB * NK * NK));
        out[0] = peak + ortho;
        out[1] = peak;
        out[2] = ortho;
    }
}

extern "C" void kernel_launch(void* const* d_in, const int* in_sizes, int n_in,
                              void* d_out, int out_size, void* d_ws, size_t ws_size,
                              hipStream_t stream) {
    const float* a = (const float*)d_in[0];
    float* out = (float*)d_out;
    float* ws = (float*)d_ws;
    float* gram  = ws;                                   // NW*768 floats
    float* rmax  = gram + (size_t)NW * 768;              // NW*32
    int*   ridxp = (int*)(rmax + (size_t)NW * 32);
    float* rlogp = (float*)(ridxp + (size_t)NW * 32);
    float* rowkl = rlogp + (size_t)NW * 32;              // 8192
    float* ortho_parts = rowkl + NB * NK;                // 512

    k_main<<<NW, 64, 0, stream>>>(a, gram, rmax, ridxp, rlogp);
    k_fin2<<<NB * NK + 512, 64, 0, stream>>>(a, gram, rmax, ridxp, rlogp,
                                             rowkl, ortho_parts);
    k_final<<<1, 256, 0, stream>>>(rowkl, ortho_parts, out);
}

// Round 11
// 35.953 us; speedup vs baseline: 1.9109x; 1.9109x over previous
//
#include <hip/hip_runtime.h>
#include <hip/hip_bf16.h>

#define NB 256
#define NK 32
#define NL 4096
#define NC 8            // L-chunks per row
#define CH 512          // chunk length
#define EPSV 1e-5f
#define PEAK_LAMBDA 0.005f
#define ORTHO_LAMBDA 20000.0f
#define LN2F 0.6931471805599453f

typedef __attribute__((ext_vector_type(8))) short short8;
typedef __attribute__((ext_vector_type(4))) float f32x4;

// ---------------- Kernel 1: fused single-pass, no LDS staging ----------------
// Round-7 geometry (proven 36.1 µs): grid = NB*NC, block = 256 (4 waves),
// 32x512 chunk per block, 4 MFMA k-steps per wave, 16 float4 in flight.
// ONE change vs round 7: sum(log2) uses 4-element PRODUCT chains
// (log2(p0*p1*p2*p3), products in [1e-20,1] — fp32-safe) -> 4x fewer
// transcendentals (134M -> 34M), freeing trans-pipe issue slots.
// NOTE: plain __launch_bounds__(256) — min-waves clause spilled (round 5).
// NOTE2: no per-block fence/atomic tail (round-8 XCD-fence serialization).
// NOTE3: geometry is a measured U-curve: NC=4 49.8 / NC=8 36.1 / NC=16 58.9 /
// 1-wave 68.7 — do not change block shape.
__global__ __launch_bounds__(256) void k_main(const float* __restrict__ a,
                                              float* __restrict__ gram,
                                              float* __restrict__ rmax,
                                              int* __restrict__ ridx,
                                              float* __restrict__ rlogp) {
    const int bc = blockIdx.x;
    const int b = bc >> 3, chk = bc & 7;
    const int tid = threadIdx.x;
    const int lane = tid & 63, wv = tid >> 6;
    const int r0 = lane & 15, hi = lane >> 4;

    // wave wv owns l in [wv*128, wv*128+128) of the chunk: 4 MFMA k-steps
    const float* __restrict__ rowA =
        a + ((size_t)b * NK + r0) * NL + chk * CH + wv * 128 + hi * 8;
    const float* __restrict__ rowB = rowA + 16 * (size_t)NL;
    const int lbase = chk * CH + wv * 128 + hi * 8;

    float mvA = -1.0f, mvB = -1.0f;
    int miA = 0, miB = 0;
    float lpA0 = 0.0f, lpA1 = 0.0f, lpB0 = 0.0f, lpB1 = 0.0f;
    f32x4 acc00 = {0.f,0.f,0.f,0.f}, acc01 = {0.f,0.f,0.f,0.f},
          acc11 = {0.f,0.f,0.f,0.f};

#pragma unroll
    for (int s = 0; s < 4; ++s) {
        float4 a0 = *reinterpret_cast<const float4*>(rowA + s * 32);
        float4 a1 = *reinterpret_cast<const float4*>(rowA + s * 32 + 4);
        float4 b0 = *reinterpret_cast<const float4*>(rowB + s * 32);
        float4 b1 = *reinterpret_cast<const float4*>(rowB + s * 32 + 4);
        float va[8] = {a0.x, a0.y, a0.z, a0.w, a1.x, a1.y, a1.z, a1.w};
        float vb[8] = {b0.x, b0.y, b0.z, b0.w, b1.x, b1.y, b1.z, b1.w};
        float xa[8], xb[8];
        const int l0 = lbase + s * 32;
        union { unsigned u[4]; short8 s8; } fa, fb;
#pragma unroll
        for (int c2 = 0; c2 < 4; ++c2) {
            float v0 = va[2*c2], v1 = va[2*c2 + 1];
            float w0 = vb[2*c2], w1 = vb[2*c2 + 1];
            float xa0 = v0 + EPSV, xa1 = v1 + EPSV;
            float xb0 = w0 + EPSV, xb1 = w1 + EPSV;
            xa[2*c2] = xa0; xa[2*c2 + 1] = xa1;
            xb[2*c2] = xb0; xb[2*c2 + 1] = xb1;
            if (v0 > mvA) { mvA = v0; miA = l0 + 2*c2; }
            if (v1 > mvA) { mvA = v1; miA = l0 + 2*c2 + 1; }
            if (w0 > mvB) { mvB = w0; miB = l0 + 2*c2; }
            if (w1 > mvB) { mvB = w1; miB = l0 + 2*c2 + 1; }
            // pack hi16(xa0) | hi16(xa1)<<16 : one v_perm_b32 per pair
            fa.u[c2] = __builtin_amdgcn_perm(__float_as_uint(xa1),
                                             __float_as_uint(xa0), 0x07060302u);
            fb.u[c2] = __builtin_amdgcn_perm(__float_as_uint(xb1),
                                             __float_as_uint(xb0), 0x07060302u);
        }
        // 4-chain product-log: log2(x0 x1 x2 x3), product in [1e-20, 1]
        lpA0 += __log2f((xa[0] * xa[1]) * (xa[2] * xa[3]));
        lpA1 += __log2f((xa[4] * xa[5]) * (xa[6] * xa[7]));
        lpB0 += __log2f((xb[0] * xb[1]) * (xb[2] * xb[3]));
        lpB1 += __log2f((xb[4] * xb[5]) * (xb[6] * xb[7]));
        acc00 = __builtin_amdgcn_mfma_f32_16x16x32_bf16(fa.s8, fa.s8, acc00, 0, 0, 0);
        acc01 = __builtin_amdgcn_mfma_f32_16x16x32_bf16(fa.s8, fb.s8, acc01, 0, 0, 0);
        acc11 = __builtin_amdgcn_mfma_f32_16x16x32_bf16(fb.s8, fb.s8, acc11, 0, 0, 0);
    }
    float lpA = (lpA0 + lpA1) * LN2F;
    float lpB = (lpB0 + lpB1) * LN2F;

    // ---- cross-lane per-row reduce: row r0 lives in lanes {r0,+16,+32,+48}
#pragma unroll
    for (int off = 16; off <= 32; off <<= 1) {
        float ov = __shfl_xor(mvA, off); int oi = __shfl_xor(miA, off);
        if (ov > mvA || (ov == mvA && oi < miA)) { mvA = ov; miA = oi; }
        ov = __shfl_xor(mvB, off); oi = __shfl_xor(miB, off);
        if (ov > mvB || (ov == mvB && oi < miB)) { mvB = ov; miB = oi; }
        lpA += __shfl_xor(lpA, off);
        lpB += __shfl_xor(lpB, off);
    }

    __shared__ float s_mv[4][32], s_lp[4][32];
    __shared__ int   s_mi[4][32];
    __shared__ float gbuf[4][768];

    if (hi == 0) {
        s_mv[wv][r0] = mvA; s_mi[wv][r0] = miA; s_lp[wv][r0] = lpA;
        s_mv[wv][16 + r0] = mvB; s_mi[wv][16 + r0] = miB; s_lp[wv][16 + r0] = lpB;
    }
    // Gram C/D layout (m89-verified): col = lane&15, row = (lane>>4)*4 + reg
    {
        const int rb2 = hi * 4;
#pragma unroll
        for (int r = 0; r < 4; ++r) {
            int gr = rb2 + r;
            gbuf[wv][gr * 16 + r0]       = acc00[r];
            gbuf[wv][256 + gr * 16 + r0] = acc01[r];
            gbuf[wv][512 + gr * 16 + r0] = acc11[r];
        }
    }
    __syncthreads();

    if (tid < 32) {  // combine 4 wave partials per row (waves ascending-l)
        float bv = -1.0f, lp = 0.0f; int bi = 0;
#pragma unroll
        for (int w = 0; w < 4; ++w) {
            float v = s_mv[w][tid]; int i = s_mi[w][tid];
            if (v > bv || (v == bv && i < bi)) { bv = v; bi = i; }
            lp += s_lp[w][tid];
        }
        rmax[bc * 32 + tid] = bv;
        ridx[bc * 32 + tid] = bi;
        rlogp[bc * 32 + tid] = lp;
    }
#pragma unroll
    for (int j = 0; j < 3; ++j) {
        int e = tid + 256 * j;
        gram[(size_t)bc * 768 + e] =
            gbuf[0][e] + gbuf[1][e] + gbuf[2][e] + gbuf[3][e];
    }
}

// ---------------- Kernel 2: parallel finalize (8704 x 64) ----------------
// Blocks 0..8191: one wave per (b,k) row — lanes 0..7 combine the 8 chunk
// partials via shfl, then the 64-wide Gaussian window maps 1:1 onto lanes
// (the gather becomes one coalesced 256B read). Butterfly reductions, no LDS.
// Blocks 8192..8703: gram finalize — each block sums 8 chunk partials for
// 384 elements, applies off-diag/2x weights, squares, butterfly-reduces.
__global__ __launch_bounds__(64) void k_fin2(const float* __restrict__ a,
                                             const float* __restrict__ gram,
                                             const float* __restrict__ rmax,
                                             const int* __restrict__ ridx,
                                             const float* __restrict__ rlogp,
                                             float* __restrict__ rowkl,
                                             float* __restrict__ ortho_parts) {
    const int bid = blockIdx.x;
    const int lane = threadIdx.x;

    if (bid < NB * NK) {
        const int b = bid >> 5, k = bid & 31;
        // lanes 0..7 hold one chunk's partials each
        float bv = -1.0f, lp = 0.0f; int bi = 0;
        if (lane < NC) {
            bv = rmax[(b * NC + lane) * 32 + k];
            bi = ridx[(b * NC + lane) * 32 + k];
            lp = rlogp[(b * NC + lane) * 32 + k];
        }
#pragma unroll
        for (int off = 1; off <= 4; off <<= 1) {
            float ov = __shfl_xor(bv, off); int oi = __shfl_xor(bi, off);
            float ol = __shfl_xor(lp, off);
            if (ov > bv || (ov == bv && oi < bi)) { bv = ov; bi = oi; }
            lp += ol;
        }
        const int idx = __shfl(bi, 0);
        const float lpr = __shfl(lp, 0);

        // window: l = idx-31+lane, one element per lane
        const int l = idx - 31 + lane;
        const float d = (float)(lane - 31);
        const bool valid = (l >= 0) && (l < NL);
        const float g = valid ? __expf(d * d * (-1.0f / 4.5f)) : 0.0f;
        const float pv = valid
            ? a[((size_t)b * NK + k) * (size_t)NL + l] : 1.0f;
        float zs = g;
#pragma unroll
        for (int off = 1; off < 64; off <<= 1) zs += __shfl_xor(zs, off);
        const float rz = 1.0f / zs;
        float term = 0.0f;
        int nv = valid ? 1 : 0;
        if (valid) {
            float gg = g * rz;
            float tf = gg + EPSV;
            term = tf * __logf(tf) - gg * __logf(pv + EPSV);
        }
#pragma unroll
        for (int off = 1; off < 64; off <<= 1) {
            term += __shfl_xor(term, off);
            nv += __shfl_xor(nv, off);
        }
        if (lane == 0)
            rowkl[bid] = term + (float)(NL - nv) * (EPSV * __logf(EPSV))
                       - EPSV * lpr;
    } else {
        const int gid = bid - NB * NK;   // 0..511; 384 elements each
        float local = 0.0f;
#pragma unroll
        for (int j = 0; j < 6; ++j) {
            int eg = gid * 384 + j * 64 + lane;     // 0..196607
            int b = eg / 768, e = eg - b * 768;
            float s = 0.0f;
#pragma unroll
            for (int ch = 0; ch < NC; ++ch)
                s += gram[(size_t)(b * NC + ch) * 768 + e];
            int blk = e >> 8, idx2 = e & 255, kk = idx2 >> 4, mm = idx2 & 15;
            float w = (blk == 1) ? 2.0f : ((kk == mm) ? 0.0f : 1.0f);
            local += w * s * s;
        }
#pragma unroll
        for (int off = 1; off < 64; off <<= 1) local += __shfl_xor(local, off);
        if (lane == 0) ortho_parts[gid] = local;
    }
}

// ---------------- Kernel 3: final 8192+512 -> scalars ----------------
__global__ __launch_bounds__(256) void k_final(const float* __restrict__ rowkl,
                                               const float* __restrict__ ortho_parts,
                                               float* __restrict__ out) {
    const int tid = threadIdx.x;
    __shared__ float s1[256], s2[256];
    float pk = 0.0f, ot = 0.0f;
#pragma unroll
    for (int j = 0; j < 32; ++j) pk += rowkl[tid + 256 * j];
    ot = ortho_parts[tid] + ortho_parts[tid + 256];
    s1[tid] = pk;
    s2[tid] = ot;
    __syncthreads();
    for (int s = 128; s > 0; s >>= 1) {
        if (tid < s) { s1[tid] += s1[tid + s]; s2[tid] += s2[tid + s]; }
        __syncthreads();
    }
    if (tid == 0) {
        float peak = PEAK_LAMBDA * s1[0];
        float ortho = ORTHO_LAMBDA * (s2[0] / (float)(NB * NK * NK));
        out[0] = peak + ortho;
        out[1] = peak;
        out[2] = ortho;
    }
}

extern "C" void kernel_launch(void* const* d_in, const int* in_sizes, int n_in,
                              void* d_out, int out_size, void* d_ws, size_t ws_size,
                              hipStream_t stream) {
    const float* a = (const float*)d_in[0];
    float* out = (float*)d_out;
    float* ws = (float*)d_ws;
    float* gram  = ws;                                   // NB*NC*768 floats
    float* rmax  = gram + (size_t)NB * NC * 768;         // NB*NC*32
    int*   ridxp = (int*)(rmax + NB * NC * 32);
    float* rlogp = (float*)(ridxp + NB * NC * 32);
    float* rowkl = rlogp + NB * NC * 32;                 // 8192
    float* ortho_parts = rowkl + NB * NK;                // 512

    k_main<<<NB * NC, 256, 0, stream>>>(a, gram, rmax, ridxp, rlogp);
    k_fin2<<<NB * NK + 512, 64, 0, stream>>>(a, gram, rmax, ridxp, rlogp,
                                             rowkl, ortho_parts);
    k_final<<<1, 256, 0, stream>>>(rowkl, ortho_parts, out);
}

// Round 12
// 35.230 us; speedup vs baseline: 1.9501x; 1.0205x over previous
//
#include <hip/hip_runtime.h>
#include <hip/hip_bf16.h>

#define NB 256
#define NK 32
#define NL 4096
#define NC 8            // L-chunks per row
#define CH 512          // chunk length
#define EPSV 1e-5f
#define PEAK_LAMBDA 0.005f
#define ORTHO_LAMBDA 20000.0f
#define LN2F 0.6931471805599453f

typedef __attribute__((ext_vector_type(8))) short short8;
typedef __attribute__((ext_vector_type(4))) float f32x4;

// ---------------- Kernel 1: fused single-pass, no LDS staging ----------------
// Round-11 kernel with ONE change: the 4 k-steps are split into an outer
// #pragma unroll 1 loop of 2x2 steps, halving in-flight load temporaries
// (16 -> 8 float4) to cut VGPR and raise waves/SIMD (the isolated occupancy
// experiment rounds 5/9 confounded).
// NOTE: plain __launch_bounds__(256) — min-waves clause spilled (round 5).
// NOTE2: no per-block fence/atomic tail (round-8 XCD-fence serialization).
// NOTE3: geometry U-curve measured: NC=4 49.8 / NC=8 36.1 / NC=16 58.9 /
// 1-wave 68.7 — do not change block shape.
__global__ __launch_bounds__(256) void k_main(const float* __restrict__ a,
                                              float* __restrict__ gram,
                                              float* __restrict__ rmax,
                                              int* __restrict__ ridx,
                                              float* __restrict__ rlogp) {
    const int bc = blockIdx.x;
    const int b = bc >> 3, chk = bc & 7;
    const int tid = threadIdx.x;
    const int lane = tid & 63, wv = tid >> 6;
    const int r0 = lane & 15, hi = lane >> 4;

    // wave wv owns l in [wv*128, wv*128+128) of the chunk: 4 MFMA k-steps
    const float* __restrict__ rowA =
        a + ((size_t)b * NK + r0) * NL + chk * CH + wv * 128 + hi * 8;
    const float* __restrict__ rowB = rowA + 16 * (size_t)NL;
    const int lbase = chk * CH + wv * 128 + hi * 8;

    float mvA = -1.0f, mvB = -1.0f;
    int miA = 0, miB = 0;
    float lpA0 = 0.0f, lpA1 = 0.0f, lpB0 = 0.0f, lpB1 = 0.0f;
    f32x4 acc00 = {0.f,0.f,0.f,0.f}, acc01 = {0.f,0.f,0.f,0.f},
          acc11 = {0.f,0.f,0.f,0.f};

#pragma unroll 1
    for (int it = 0; it < 2; ++it) {
#pragma unroll
        for (int si = 0; si < 2; ++si) {
            const int s = it * 2 + si;
            float4 a0 = *reinterpret_cast<const float4*>(rowA + s * 32);
            float4 a1 = *reinterpret_cast<const float4*>(rowA + s * 32 + 4);
            float4 b0 = *reinterpret_cast<const float4*>(rowB + s * 32);
            float4 b1 = *reinterpret_cast<const float4*>(rowB + s * 32 + 4);
            float va[8] = {a0.x, a0.y, a0.z, a0.w, a1.x, a1.y, a1.z, a1.w};
            float vb[8] = {b0.x, b0.y, b0.z, b0.w, b1.x, b1.y, b1.z, b1.w};
            float xa[8], xb[8];
            const int l0 = lbase + s * 32;
            union { unsigned u[4]; short8 s8; } fa, fb;
#pragma unroll
            for (int c2 = 0; c2 < 4; ++c2) {
                float v0 = va[2*c2], v1 = va[2*c2 + 1];
                float w0 = vb[2*c2], w1 = vb[2*c2 + 1];
                float xa0 = v0 + EPSV, xa1 = v1 + EPSV;
                float xb0 = w0 + EPSV, xb1 = w1 + EPSV;
                xa[2*c2] = xa0; xa[2*c2 + 1] = xa1;
                xb[2*c2] = xb0; xb[2*c2 + 1] = xb1;
                if (v0 > mvA) { mvA = v0; miA = l0 + 2*c2; }
                if (v1 > mvA) { mvA = v1; miA = l0 + 2*c2 + 1; }
                if (w0 > mvB) { mvB = w0; miB = l0 + 2*c2; }
                if (w1 > mvB) { mvB = w1; miB = l0 + 2*c2 + 1; }
                // pack hi16(x0) | hi16(x1)<<16 : one v_perm_b32 per pair
                fa.u[c2] = __builtin_amdgcn_perm(__float_as_uint(xa1),
                                                 __float_as_uint(xa0),
                                                 0x07060302u);
                fb.u[c2] = __builtin_amdgcn_perm(__float_as_uint(xb1),
                                                 __float_as_uint(xb0),
                                                 0x07060302u);
            }
            // 4-chain product-log: log2(x0 x1 x2 x3), product in [1e-20, 1]
            lpA0 += __log2f((xa[0] * xa[1]) * (xa[2] * xa[3]));
            lpA1 += __log2f((xa[4] * xa[5]) * (xa[6] * xa[7]));
            lpB0 += __log2f((xb[0] * xb[1]) * (xb[2] * xb[3]));
            lpB1 += __log2f((xb[4] * xb[5]) * (xb[6] * xb[7]));
            acc00 = __builtin_amdgcn_mfma_f32_16x16x32_bf16(fa.s8, fa.s8, acc00, 0, 0, 0);
            acc01 = __builtin_amdgcn_mfma_f32_16x16x32_bf16(fa.s8, fb.s8, acc01, 0, 0, 0);
            acc11 = __builtin_amdgcn_mfma_f32_16x16x32_bf16(fb.s8, fb.s8, acc11, 0, 0, 0);
        }
    }
    float lpA = (lpA0 + lpA1) * LN2F;
    float lpB = (lpB0 + lpB1) * LN2F;

    // ---- cross-lane per-row reduce: row r0 lives in lanes {r0,+16,+32,+48}
#pragma unroll
    for (int off = 16; off <= 32; off <<= 1) {
        float ov = __shfl_xor(mvA, off); int oi = __shfl_xor(miA, off);
        if (ov > mvA || (ov == mvA && oi < miA)) { mvA = ov; miA = oi; }
        ov = __shfl_xor(mvB, off); oi = __shfl_xor(miB, off);
        if (ov > mvB || (ov == mvB && oi < miB)) { mvB = ov; miB = oi; }
        lpA += __shfl_xor(lpA, off);
        lpB += __shfl_xor(lpB, off);
    }

    __shared__ float s_mv[4][32], s_lp[4][32];
    __shared__ int   s_mi[4][32];
    __shared__ float gbuf[4][768];

    if (hi == 0) {
        s_mv[wv][r0] = mvA; s_mi[wv][r0] = miA; s_lp[wv][r0] = lpA;
        s_mv[wv][16 + r0] = mvB; s_mi[wv][16 + r0] = miB; s_lp[wv][16 + r0] = lpB;
    }
    // Gram C/D layout (m89-verified): col = lane&15, row = (lane>>4)*4 + reg
    {
        const int rb2 = hi * 4;
#pragma unroll
        for (int r = 0; r < 4; ++r) {
            int gr = rb2 + r;
            gbuf[wv][gr * 16 + r0]       = acc00[r];
            gbuf[wv][256 + gr * 16 + r0] = acc01[r];
            gbuf[wv][512 + gr * 16 + r0] = acc11[r];
        }
    }
    __syncthreads();

    if (tid < 32) {  // combine 4 wave partials per row (waves ascending-l)
        float bv = -1.0f, lp = 0.0f; int bi = 0;
#pragma unroll
        for (int w = 0; w < 4; ++w) {
            float v = s_mv[w][tid]; int i = s_mi[w][tid];
            if (v > bv || (v == bv && i < bi)) { bv = v; bi = i; }
            lp += s_lp[w][tid];
        }
        rmax[bc * 32 + tid] = bv;
        ridx[bc * 32 + tid] = bi;
        rlogp[bc * 32 + tid] = lp;
    }
#pragma unroll
    for (int j = 0; j < 3; ++j) {
        int e = tid + 256 * j;
        gram[(size_t)bc * 768 + e] =
            gbuf[0][e] + gbuf[1][e] + gbuf[2][e] + gbuf[3][e];
    }
}

// ---------------- Kernel 2: parallel finalize (8704 x 64) ----------------
// Blocks 0..8191: one wave per (b,k) row — lanes 0..7 combine the 8 chunk
// partials via shfl, then the 64-wide Gaussian window maps 1:1 onto lanes
// (the gather becomes one coalesced 256B read). Butterfly reductions, no LDS.
// Blocks 8192..8703: gram finalize — each block sums 8 chunk partials for
// 384 elements, applies off-diag/2x weights, squares, butterfly-reduces.
__global__ __launch_bounds__(64) void k_fin2(const float* __restrict__ a,
                                             const float* __restrict__ gram,
                                             const float* __restrict__ rmax,
                                             const int* __restrict__ ridx,
                                             const float* __restrict__ rlogp,
                                             float* __restrict__ rowkl,
                                             float* __restrict__ ortho_parts) {
    const int bid = blockIdx.x;
    const int lane = threadIdx.x;

    if (bid < NB * NK) {
        const int b = bid >> 5, k = bid & 31;
        // lanes 0..7 hold one chunk's partials each
        float bv = -1.0f, lp = 0.0f; int bi = 0;
        if (lane < NC) {
            bv = rmax[(b * NC + lane) * 32 + k];
            bi = ridx[(b * NC + lane) * 32 + k];
            lp = rlogp[(b * NC + lane) * 32 + k];
        }
#pragma unroll
        for (int off = 1; off <= 4; off <<= 1) {
            float ov = __shfl_xor(bv, off); int oi = __shfl_xor(bi, off);
            float ol = __shfl_xor(lp, off);
            if (ov > bv || (ov == bv && oi < bi)) { bv = ov; bi = oi; }
            lp += ol;
        }
        const int idx = __shfl(bi, 0);
        const float lpr = __shfl(lp, 0);

        // window: l = idx-31+lane, one element per lane
        const int l = idx - 31 + lane;
        const float d = (float)(lane - 31);
        const bool valid = (l >= 0) && (l < NL);
        const float g = valid ? __expf(d * d * (-1.0f / 4.5f)) : 0.0f;
        const float pv = valid
            ? a[((size_t)b * NK + k) * (size_t)NL + l] : 1.0f;
        float zs = g;
#pragma unroll
        for (int off = 1; off < 64; off <<= 1) zs += __shfl_xor(zs, off);
        const float rz = 1.0f / zs;
        float term = 0.0f;
        int nv = valid ? 1 : 0;
        if (valid) {
            float gg = g * rz;
            float tf = gg + EPSV;
            term = tf * __logf(tf) - gg * __logf(pv + EPSV);
        }
#pragma unroll
        for (int off = 1; off < 64; off <<= 1) {
            term += __shfl_xor(term, off);
            nv += __shfl_xor(nv, off);
        }
        if (lane == 0)
            rowkl[bid] = term + (float)(NL - nv) * (EPSV * __logf(EPSV))
                       - EPSV * lpr;
    } else {
        const int gid = bid - NB * NK;   // 0..511; 384 elements each
        float local = 0.0f;
#pragma unroll
        for (int j = 0; j < 6; ++j) {
            int eg = gid * 384 + j * 64 + lane;     // 0..196607
            int b = eg / 768, e = eg - b * 768;
            float s = 0.0f;
#pragma unroll
            for (int ch = 0; ch < NC; ++ch)
                s += gram[(size_t)(b * NC + ch) * 768 + e];
            int blk = e >> 8, idx2 = e & 255, kk = idx2 >> 4, mm = idx2 & 15;
            float w = (blk == 1) ? 2.0f : ((kk == mm) ? 0.0f : 1.0f);
            local += w * s * s;
        }
#pragma unroll
        for (int off = 1; off < 64; off <<= 1) local += __shfl_xor(local, off);
        if (lane == 0) ortho_parts[gid] = local;
    }
}

// ---------------- Kernel 3: final 8192+512 -> scalars ----------------
__global__ __launch_bounds__(256) void k_final(const float* __restrict__ rowkl,
                                               const float* __restrict__ ortho_parts,
                                               float* __restrict__ out) {
    const int tid = threadIdx.x;
    __shared__ float s1[256], s2[256];
    float pk = 0.0f, ot = 0.0f;
#pragma unroll
    for (int j = 0; j < 32; ++j) pk += rowkl[tid + 256 * j];
    ot = ortho_parts[tid] + ortho_parts[tid + 256];
    s1[tid] = pk;
    s2[tid] = ot;
    __syncthreads();
    for (int s = 128; s > 0; s >>= 1) {
        if (tid < s) { s1[tid] += s1[tid + s]; s2[tid] += s2[tid + s]; }
        __syncthreads();
    }
    if (tid == 0) {
        float peak = PEAK_LAMBDA * s1[0];
        float ortho = ORTHO_LAMBDA * (s2[0] / (float)(NB * NK * NK));
        out[0] = peak + ortho;
        out[1] = peak;
        out[2] = ortho;
    }
}

extern "C" void kernel_launch(void* const* d_in, const int* in_sizes, int n_in,
                              void* d_out, int out_size, void* d_ws, size_t ws_size,
                              hipStream_t stream) {
    const float* a = (const float*)d_in[0];
    float* out = (float*)d_out;
    float* ws = (float*)d_ws;
    float* gram  = ws;                                   // NB*NC*768 floats
    float* rmax  = gram + (size_t)NB * NC * 768;         // NB*NC*32
    int*   ridxp = (int*)(rmax + NB * NC * 32);
    float* rlogp = (float*)(ridxp + NB * NC * 32);
    float* rowkl = rlogp + NB * NC * 32;                 // 8192
    float* ortho_parts = rowkl + NB * NK;                // 512

    k_main<<<NB * NC, 256, 0, stream>>>(a, gram, rmax, ridxp, rlogp);
    k_fin2<<<NB * NK + 512, 64, 0, stream>>>(a, gram, rmax, ridxp, rlogp,
                                             rowkl, ortho_parts);
    k_final<<<1, 256, 0, stream>>>(rowkl, ortho_parts, out);
}